// Round 15
// baseline (304.806 us; speedup 1.0000x reference)
//
#include <hip/hip_runtime.h>

#define NV   100000
#define NE   50000
#define NNZ  3200000
#define KIN  256
#define KOUT 64

#define NBL   64                   // partition/hist blocks (NNZ = 64*50000 exactly)
#define CHUNK (NNZ / NBL)          // 50000
#define NBKT  782                  // buckets per side: E = 64 edges, V = 128 verts
#define NBINS (2 * NBKT)           // 1564
#define LSCAN (NBINS * NBL)        // 100096
#define NBLK_SCAN ((LSCAN + 1023) / 1024)   // 98

#define ECAP_E 6144                // E-bucket sbuf capacity (mean 4096)
#define ECAP_V 4608                // V-bucket sbuf capacity (mean 4096, sigma 64)
#define PCAP  (NNZ + 8192)         // part array capacity incl. 8-entry bucket padding
#define FINF  0x7FFFFFFF

typedef short short8 __attribute__((ext_vector_type(8)));
typedef float f32x4  __attribute__((ext_vector_type(4)));

__device__ __forceinline__ unsigned short f2bf(float f) {
    union { float f; unsigned u; } c{f};
    const unsigned lsb = (c.u >> 16) & 1u;
    return (unsigned short)((c.u + 0x7FFFu + lsb) >> 16);
}
__device__ __forceinline__ float bf2f_lo(unsigned u) {
    union { unsigned u; float f; } c{u << 16};
    return c.f;
}
__device__ __forceinline__ float bf2f_hi(unsigned u) {
    union { unsigned u; float f; } c{u & 0xFFFF0000u};
    return c.f;
}
__device__ __forceinline__ short8 pack8(const float4 lo, const float4 hi) {
    short8 r;
    r[0] = (short)f2bf(lo.x); r[1] = (short)f2bf(lo.y);
    r[2] = (short)f2bf(lo.z); r[3] = (short)f2bf(lo.w);
    r[4] = (short)f2bf(hi.x); r[5] = (short)f2bf(hi.y);
    r[6] = (short)f2bf(hi.z); r[7] = (short)f2bf(hi.w);
    return r;
}

// ---------------------------------------------------------------------------
// One-off: Wb[o][k] = bf16(W[o][k])
// ---------------------------------------------------------------------------
__global__ __launch_bounds__(256) void k_wb(const float* __restrict__ W,
                                            unsigned short* __restrict__ Wb) {
    const int i = blockIdx.x * 256 + threadIdx.x;
    Wb[i] = f2bf(W[i]);
}

// ---------------------------------------------------------------------------
// Kernel 1: zero-LDS bf16 MFMA GEMM (round-10, verified absmax 1.0)
// ---------------------------------------------------------------------------
__global__ __launch_bounds__(256) void k_project(const float* __restrict__ X,
                                                 const unsigned short* __restrict__ Wb,
                                                 unsigned short* __restrict__ Xpb) {
    const int tid  = threadIdx.x;
    const int lane = tid & 63;
    const int wv   = tid >> 6;
    const int l15  = lane & 15;
    const int l4   = lane >> 4;
    const int rbase = blockIdx.x * 128 + wv * 32;

    const int r0 = min(rbase + l15,      NV - 1);
    const int r1 = min(rbase + 16 + l15, NV - 1);
    const float* xp0 = X + (size_t)r0 * KIN + l4 * 8;
    const float* xp1 = X + (size_t)r1 * KIN + l4 * 8;
    const unsigned short* wp = Wb + (size_t)l15 * KIN + l4 * 8;

    f32x4 acc[2][4];
#pragma unroll
    for (int t = 0; t < 2; ++t)
#pragma unroll
        for (int g = 0; g < 4; ++g)
            acc[t][g] = (f32x4){0.f, 0.f, 0.f, 0.f};

#pragma unroll
    for (int s = 0; s < 8; ++s) {
        const int k0 = s * 32;
        const float4 a0lo = *(const float4*)(xp0 + k0);
        const float4 a0hi = *(const float4*)(xp0 + k0 + 4);
        const float4 a1lo = *(const float4*)(xp1 + k0);
        const float4 a1hi = *(const float4*)(xp1 + k0 + 4);
        short8 b[4];
#pragma unroll
        for (int g = 0; g < 4; ++g)
            b[g] = *(const short8*)(wp + (size_t)g * 16 * KIN + k0);
        const short8 a0 = pack8(a0lo, a0hi);
        const short8 a1 = pack8(a1lo, a1hi);
#pragma unroll
        for (int g = 0; g < 4; ++g) {
            acc[0][g] = __builtin_amdgcn_mfma_f32_16x16x32_bf16(a0, b[g], acc[0][g], 0, 0, 0);
            acc[1][g] = __builtin_amdgcn_mfma_f32_16x16x32_bf16(a1, b[g], acc[1][g], 0, 0, 0);
        }
    }

#pragma unroll
    for (int t = 0; t < 2; ++t)
#pragma unroll
        for (int i = 0; i < 4; ++i) {
            const int r = rbase + t * 16 + l4 * 4 + i;
            if (r < NV) {
#pragma unroll
                for (int g = 0; g < 4; ++g)
                    Xpb[(size_t)r * KOUT + g * 16 + l15] = f2bf(acc[t][g][i]);
            }
        }
}

// ---------------------------------------------------------------------------
// Per-block LDS histogram of BOTH bucket keys -> count matrix
// E bins: e>>6 (rows 0..781); V bins: v>>7 (rows 782..1563)
// ---------------------------------------------------------------------------
__global__ __launch_bounds__(1024) void k_hist(const int* __restrict__ v_idx,
                                               const int* __restrict__ e_idx,
                                               int* __restrict__ mat) {
    __shared__ int h[NBINS];
    const int b = blockIdx.x, tid = threadIdx.x;
    for (int i = tid; i < NBINS; i += 1024) h[i] = 0;
    __syncthreads();
    const int base = b * CHUNK;
    for (int i = tid; i < CHUNK; i += 1024) {
        atomicAdd(&h[e_idx[base + i] >> 6], 1);
        atomicAdd(&h[NBKT + (v_idx[base + i] >> 7)], 1);
    }
    __syncthreads();
    for (int j = tid; j < NBINS; j += 1024) mat[j * NBL + b] = h[j];
}

// ---------------------------------------------------------------------------
// 3-kernel exclusive scan of mat[LSCAN]
// ---------------------------------------------------------------------------
__global__ __launch_bounds__(1024) void k_scan1(int* __restrict__ mat,
                                                int* __restrict__ bsum) {
    __shared__ int buf[1024];
    const int tid = threadIdx.x;
    const int i = blockIdx.x * 1024 + tid;
    const int v = (i < LSCAN) ? mat[i] : 0;
    buf[tid] = v;
    __syncthreads();
    for (int d = 1; d < 1024; d <<= 1) {
        int t = (tid >= d) ? buf[tid - d] : 0;
        __syncthreads();
        buf[tid] += t;
        __syncthreads();
    }
    if (i < LSCAN) mat[i] = buf[tid] - v;
    if (tid == 1023) bsum[blockIdx.x] = buf[1023];
}

__global__ __launch_bounds__(1024) void k_scan2(int* __restrict__ bsum) {
    __shared__ int buf[1024];
    const int tid = threadIdx.x;
    const int v = (tid < NBLK_SCAN) ? bsum[tid] : 0;
    buf[tid] = v;
    __syncthreads();
    for (int d = 1; d < 1024; d <<= 1) {
        int t = (tid >= d) ? buf[tid - d] : 0;
        __syncthreads();
        buf[tid] += t;
        __syncthreads();
    }
    if (tid < NBLK_SCAN) bsum[tid] = buf[tid] - v;
}

__global__ __launch_bounds__(1024) void k_scan3(int* __restrict__ mat,
                                                const int* __restrict__ bsum) {
    const int i = blockIdx.x * 1024 + threadIdx.x;
    if (i < LSCAN) mat[i] += bsum[blockIdx.x];
}

// ---------------------------------------------------------------------------
// Padded bucket starts (8-entry / 32 B aligned) so sector flushes never span
// buckets. psX[j] = exclusive scan of align8(bucket count).
// ---------------------------------------------------------------------------
__global__ __launch_bounds__(1024) void k_pad(const int* __restrict__ mat,
                                              int* __restrict__ psE,
                                              int* __restrict__ psV) {
    __shared__ int buf[1024];
    const int tid = threadIdx.x;
    int c = 0;
    if (tid < NBKT) {
        const int s = mat[tid * NBL];
        const int e = (tid == NBKT - 1) ? NNZ : mat[(tid + 1) * NBL];
        c = (e - s + 7) & ~7;
    }
    buf[tid] = c;
    __syncthreads();
    for (int d = 1; d < 1024; d <<= 1) {
        int t = (tid >= d) ? buf[tid - d] : 0;
        __syncthreads();
        buf[tid] += t;
        __syncthreads();
    }
    if (tid < NBKT) psE[tid] = buf[tid] - c;
    __syncthreads();
    c = 0;
    if (tid < NBKT) {
        const int s = mat[(NBKT + tid) * NBL];
        const int e = (tid == NBKT - 1) ? 2 * NNZ : mat[(NBKT + tid + 1) * NBL];
        c = (e - s + 7) & ~7;
    }
    buf[tid] = c;
    __syncthreads();
    for (int d = 1; d < 1024; d <<= 1) {
        int t = (tid >= d) ? buf[tid - d] : 0;
        __syncthreads();
        buf[tid] += t;
        __syncthreads();
    }
    if (tid < NBKT) psV[tid] = buf[tid] - c;
}

// ---------------------------------------------------------------------------
// Write-combined partition (SIDE 0 = E, 1 = V). Per bucket: two-sector LDS
// stage (16 u32, parity-indexed); post-tile flush emits full 32 B sectors.
// Head partials + rare >=2-sector overshoots direct-store (bucket degrades).
// Positions from atomicAdd are dense -> staged sectors are always complete.
// ---------------------------------------------------------------------------
template <int SIDE>
__global__ __launch_bounds__(1024) void k_partwc(const int* __restrict__ v_idx,
                                                 const int* __restrict__ e_idx,
                                                 const int* __restrict__ mat,
                                                 const int* __restrict__ ps,
                                                 unsigned* __restrict__ part) {
    __shared__ int pos[NBKT], fsec[NBKT];
    __shared__ unsigned char bad[NBKT];
    __shared__ unsigned stg[NBKT * 16];      // 50 KB
    const int b = blockIdx.x, tid = threadIdx.x;
    const int jOff = SIDE ? NBKT : 0;

    for (int j = tid; j < NBKT; j += 1024) {
        const int p = ps[j] + (mat[(jOff + j) * NBL + b] - mat[(jOff + j) * NBL]);
        pos[j] = p;
        fsec[j] = (p + 7) >> 3;
        bad[j] = 0;
    }
    __syncthreads();

    const int base = b * CHUNK;
    for (int t0 = 0; t0 < CHUNK; t0 += 1024) {
        if (t0 + tid < CHUNK) {
            const int i = base + t0 + tid;
            const int v = v_idx[i], e = e_idx[i];
            int j; unsigned val;
            if (SIDE == 0) { j = e >> 6; val = (unsigned)v | ((unsigned)(e & 63) << 17); }
            else           { j = v >> 7; val = (unsigned)e | ((unsigned)(v & 127) << 16); }
            const int g = atomicAdd(&pos[j], 1);
            const int sec = g >> 3;
            const int fs = fsec[j];
            if (fs != FINF && sec >= fs && sec <= fs + 1) {
                stg[j * 16 + (sec & 1) * 8 + (g & 7)] = val;
                if (bad[j]) part[g] = val;   // degraded bucket: also direct
            } else {
                part[g] = val;               // head partial / overshoot / degraded
                if (fs != FINF && sec > fs + 1) bad[j] = 1;
            }
        }
        __syncthreads();
        if (tid < NBKT) {
            const int j = tid;
            int fs = fsec[j];
            if (fs != FINF) {
                if (!bad[j]) {
                    const int lim = pos[j] >> 3;
                    while (fs < lim) {
                        uint4* dst = (uint4*)&part[fs << 3];
                        const unsigned* s = &stg[j * 16 + (fs & 1) * 8];
                        dst[0] = make_uint4(s[0], s[1], s[2], s[3]);
                        dst[1] = make_uint4(s[4], s[5], s[6], s[7]);
                        ++fs;
                    }
                    fsec[j] = fs;
                } else {
                    // degrade: drain staged region [fs*8, min(pos,(fs+2)*8)), then all-direct
                    const int hi = min(pos[j], (fs + 2) << 3);
                    for (int g = fs << 3; g < hi; ++g)
                        part[g] = stg[j * 16 + ((g >> 3) & 1) * 8 + (g & 7)];
                    fsec[j] = FINF;
                }
            }
        }
        __syncthreads();
    }
    // final partial-sector drain for clean buckets
    if (tid < NBKT) {
        const int j = tid;
        const int fs = fsec[j];
        if (fs != FINF && !bad[j]) {
            for (int g = fs << 3; g < pos[j]; ++g)
                part[g] = stg[j * 16 + ((g >> 3) & 1) * 8 + (g & 7)];
        }
    }
}

// ---------------------------------------------------------------------------
// Fused sort+gather, edge side (64-edge buckets): counting sort in LDS, then
// quarter-wave register gather; coalesced bf16 row writes.
// ---------------------------------------------------------------------------
__global__ __launch_bounds__(1024) void k_sortgatherE(const unsigned* __restrict__ part,
                                                      const int* __restrict__ mat,
                                                      const int* __restrict__ psE,
                                                      const unsigned short* __restrict__ Xpb,
                                                      const float* __restrict__ degE,
                                                      const float* __restrict__ Wdiag,
                                                      unsigned short* __restrict__ Xeb) {
    __shared__ unsigned sbuf[ECAP_E];       // 24 KB
    __shared__ int hist[64], cur[64], pfx[65];
    const int b = blockIdx.x, tid = threadIdx.x;
    const int base = psE[b];
    const int nb = ((b == NBKT - 1) ? NNZ : mat[(b + 1) * NBL]) - mat[b * NBL];

    if (tid < 64) hist[tid] = 0;
    __syncthreads();
    for (int i = tid; i < nb; i += 1024)
        atomicAdd(&hist[(part[base + i] >> 17) & 63], 1);
    __syncthreads();
    if (tid == 0) {
        int s = 0;
        for (int k = 0; k < 64; ++k) { pfx[k] = s; cur[k] = s; s += hist[k]; }
        pfx[64] = s;
    }
    __syncthreads();
    for (int i = tid; i < nb; i += 1024) {
        const unsigned u = part[base + i];
        const int p = atomicAdd(&cur[(u >> 17) & 63], 1);
        sbuf[p] = u & 0x1FFFFu;
    }
    __syncthreads();

    const int wv = tid >> 6, lane = tid & 63;
    const int q = lane >> 4, sl = lane & 15;
#pragma unroll
    for (int j = 0; j < 4; ++j) {
        const int le = wv * 4 + j;
        const int e_id = (b << 6) + le;
        const int s0 = pfx[le];
        const int n  = pfx[le + 1] - s0;
        float a0 = 0.f, a1 = 0.f, a2 = 0.f, a3 = 0.f;
        const int nf = n >> 2;
        int t = 0;
        for (; t + 4 <= nf; t += 4) {
            int idx[4]; uint2 u4[4];
#pragma unroll
            for (int z = 0; z < 4; ++z) idx[z] = (int)sbuf[s0 + 4 * (t + z) + q];
#pragma unroll
            for (int z = 0; z < 4; ++z)
                u4[z] = *(const uint2*)&Xpb[(size_t)idx[z] * KOUT + 4 * sl];
#pragma unroll
            for (int z = 0; z < 4; ++z) {
                a0 += bf2f_lo(u4[z].x); a1 += bf2f_hi(u4[z].x);
                a2 += bf2f_lo(u4[z].y); a3 += bf2f_hi(u4[z].y);
            }
        }
        for (; t < nf; ++t) {
            const int idx = (int)sbuf[s0 + 4 * t + q];
            const uint2 u = *(const uint2*)&Xpb[(size_t)idx * KOUT + 4 * sl];
            a0 += bf2f_lo(u.x); a1 += bf2f_hi(u.x);
            a2 += bf2f_lo(u.y); a3 += bf2f_hi(u.y);
        }
        if (n & 3) {
            const int src = nf * 4 + q;
            if (src < n) {
                const int idx = (int)sbuf[s0 + src];
                const uint2 u = *(const uint2*)&Xpb[(size_t)idx * KOUT + 4 * sl];
                a0 += bf2f_lo(u.x); a1 += bf2f_hi(u.x);
                a2 += bf2f_lo(u.y); a3 += bf2f_hi(u.y);
            }
        }
        a0 += __shfl_xor(a0, 16, 64); a0 += __shfl_xor(a0, 32, 64);
        a1 += __shfl_xor(a1, 16, 64); a1 += __shfl_xor(a1, 32, 64);
        a2 += __shfl_xor(a2, 16, 64); a2 += __shfl_xor(a2, 32, 64);
        a3 += __shfl_xor(a3, 16, 64); a3 += __shfl_xor(a3, 32, 64);
        if (q == 0 && e_id < NE) {
            const float s = degE[e_id] * Wdiag[e_id];
            uint2 pk;
            pk.x = (unsigned)f2bf(a0 * s) | ((unsigned)f2bf(a1 * s) << 16);
            pk.y = (unsigned)f2bf(a2 * s) | ((unsigned)f2bf(a3 * s) << 16);
            *(uint2*)&Xeb[(size_t)e_id * KOUT + 4 * sl] = pk;
        }
    }
}

// ---------------------------------------------------------------------------
// Fused sort+gather, vertex side (128-vertex buckets): f32 out.
// partV entry = e | (v&127)<<16.
// ---------------------------------------------------------------------------
__global__ __launch_bounds__(1024) void k_sortgatherV(const unsigned* __restrict__ part,
                                                      const int* __restrict__ mat,
                                                      const int* __restrict__ psV,
                                                      const unsigned short* __restrict__ Xeb,
                                                      const float* __restrict__ degV,
                                                      float* __restrict__ out) {
    __shared__ unsigned sbuf[ECAP_V];       // 18 KB
    __shared__ int hist[128], cur[128], pfx[129];
    const int b = blockIdx.x, tid = threadIdx.x;
    const int base = psV[b];
    const int nb = ((b == NBKT - 1) ? 2 * NNZ : mat[(NBKT + b + 1) * NBL]) - mat[(NBKT + b) * NBL];

    if (tid < 128) hist[tid] = 0;
    __syncthreads();
    for (int i = tid; i < nb; i += 1024)
        atomicAdd(&hist[(part[base + i] >> 16) & 127], 1);
    __syncthreads();
    if (tid == 0) {
        int s = 0;
        for (int k = 0; k < 128; ++k) { pfx[k] = s; cur[k] = s; s += hist[k]; }
        pfx[128] = s;
    }
    __syncthreads();
    for (int i = tid; i < nb; i += 1024) {
        const unsigned u = part[base + i];
        const int p = atomicAdd(&cur[(u >> 16) & 127], 1);
        sbuf[p] = u & 0xFFFFu;
    }
    __syncthreads();

    const int wv = tid >> 6, lane = tid & 63;
    const int q = lane >> 4, sl = lane & 15;
#pragma unroll
    for (int j = 0; j < 8; ++j) {
        const int lv = wv * 8 + j;
        const int v_id = (b << 7) + lv;
        const int s0 = pfx[lv];
        const int n  = pfx[lv + 1] - s0;
        float a0 = 0.f, a1 = 0.f, a2 = 0.f, a3 = 0.f;
        const int nf = n >> 2;
        int t = 0;
        for (; t + 4 <= nf; t += 4) {
            int idx[4]; uint2 u4[4];
#pragma unroll
            for (int z = 0; z < 4; ++z) idx[z] = (int)sbuf[s0 + 4 * (t + z) + q];
#pragma unroll
            for (int z = 0; z < 4; ++z)
                u4[z] = *(const uint2*)&Xeb[(size_t)idx[z] * KOUT + 4 * sl];
#pragma unroll
            for (int z = 0; z < 4; ++z) {
                a0 += bf2f_lo(u4[z].x); a1 += bf2f_hi(u4[z].x);
                a2 += bf2f_lo(u4[z].y); a3 += bf2f_hi(u4[z].y);
            }
        }
        for (; t < nf; ++t) {
            const int idx = (int)sbuf[s0 + 4 * t + q];
            const uint2 u = *(const uint2*)&Xeb[(size_t)idx * KOUT + 4 * sl];
            a0 += bf2f_lo(u.x); a1 += bf2f_hi(u.x);
            a2 += bf2f_lo(u.y); a3 += bf2f_hi(u.y);
        }
        if (n & 3) {
            const int src = nf * 4 + q;
            if (src < n) {
                const int idx = (int)sbuf[s0 + src];
                const uint2 u = *(const uint2*)&Xeb[(size_t)idx * KOUT + 4 * sl];
                a0 += bf2f_lo(u.x); a1 += bf2f_hi(u.x);
                a2 += bf2f_lo(u.y); a3 += bf2f_hi(u.y);
            }
        }
        a0 += __shfl_xor(a0, 16, 64); a0 += __shfl_xor(a0, 32, 64);
        a1 += __shfl_xor(a1, 16, 64); a1 += __shfl_xor(a1, 32, 64);
        a2 += __shfl_xor(a2, 16, 64); a2 += __shfl_xor(a2, 32, 64);
        a3 += __shfl_xor(a3, 16, 64); a3 += __shfl_xor(a3, 32, 64);
        if (q == 0 && v_id < NV) {
            const float s = degV[v_id];
            *(float4*)&out[(size_t)v_id * KOUT + 4 * sl] =
                make_float4(a0 * s, a1 * s, a2 * s, a3 * s);
        }
    }
}

extern "C" void kernel_launch(void* const* d_in, const int* in_sizes, int n_in,
                              void* d_out, int out_size, void* d_ws, size_t ws_size,
                              hipStream_t stream) {
    const float* X     = (const float*)d_in[0];
    const float* W     = (const float*)d_in[1];
    const float* degE  = (const float*)d_in[2];
    const float* degV  = (const float*)d_in[3];
    const float* Wdiag = (const float*)d_in[4];
    const int*   v_idx = (const int*)d_in[5];
    const int*   e_idx = (const int*)d_in[6];
    float* out = (float*)d_out;

    // Workspace (~46 MB)
    unsigned short* Xpb  = (unsigned short*)d_ws;             // NV*KOUT bf16
    unsigned short* Xeb  = Xpb + (size_t)NV * KOUT;           // NE*KOUT bf16
    unsigned*       partE = (unsigned*)(Xeb + (size_t)NE * KOUT); // PCAP u32
    unsigned*       partV = partE + PCAP;                     // PCAP u32
    int*            mat   = (int*)(partV + PCAP);             // LSCAN
    int*            bsum  = mat + LSCAN;                      // NBLK_SCAN (pad 128)
    int*            psE   = bsum + 128;                       // NBKT
    int*            psV   = psE + NBKT;                       // NBKT
    unsigned short* Wb    = (unsigned short*)(psV + NBKT);    // 32 KB

    k_wb<<<(KIN * KOUT) / 256, 256, 0, stream>>>(W, Wb);
    k_project<<<(NV + 127) / 128, 256, 0, stream>>>(X, Wb, Xpb);

    k_hist<<<NBL, 1024, 0, stream>>>(v_idx, e_idx, mat);
    k_scan1<<<NBLK_SCAN, 1024, 0, stream>>>(mat, bsum);
    k_scan2<<<1, 1024, 0, stream>>>(bsum);
    k_scan3<<<NBLK_SCAN, 1024, 0, stream>>>(mat, bsum);
    k_pad<<<1, 1024, 0, stream>>>(mat, psE, psV);

    // Write-combined partitions (full 32 B sector stores)
    k_partwc<0><<<NBL, 1024, 0, stream>>>(v_idx, e_idx, mat, psE, partE);
    k_partwc<1><<<NBL, 1024, 0, stream>>>(v_idx, e_idx, mat, psV, partV);

    // Fused per-bucket sort + gather
    k_sortgatherE<<<NBKT, 1024, 0, stream>>>(partE, mat, psE, Xpb, degE, Wdiag, Xeb);
    k_sortgatherV<<<NBKT, 1024, 0, stream>>>(partV, mat, psV, Xeb, degV, out);
}

// Round 16
// 266.794 us; speedup vs baseline: 1.1425x; 1.1425x over previous
//
#include <hip/hip_runtime.h>

#define NV   100000
#define NE   50000
#define NNZ  3200000
#define KIN  256
#define KOUT 64

#define NB    128                  // hist/partition chunks (NNZ = 128*25000 exactly)
#define CHUNK (NNZ / NB)           // 25000
#define NBE   782                  // ceil(NE/64) edge buckets
#define NBV   1563                 // ceil(NV/64) vertex buckets
#define NBINS (NBE + NBV)          // 2345
#define LSCAN (NBINS * NB)         // 300160
#define NBLK_SCAN ((LSCAN + 1023) / 1024)   // 294 (<= 1024 for k_scan2)

#define ECAP_E 6144                // E-bucket LDS capacity (mean 4096)
#define ECAP_V 4096                // V-bucket LDS capacity (mean 2048)

typedef short short8 __attribute__((ext_vector_type(8)));
typedef float f32x4  __attribute__((ext_vector_type(4)));

__device__ __forceinline__ unsigned short f2bf(float f) {
    union { float f; unsigned u; } c{f};
    const unsigned lsb = (c.u >> 16) & 1u;
    return (unsigned short)((c.u + 0x7FFFu + lsb) >> 16);
}
__device__ __forceinline__ float bf2f_lo(unsigned u) {
    union { unsigned u; float f; } c{u << 16};
    return c.f;
}
__device__ __forceinline__ float bf2f_hi(unsigned u) {
    union { unsigned u; float f; } c{u & 0xFFFF0000u};
    return c.f;
}
__device__ __forceinline__ short8 pack8(const float4 lo, const float4 hi) {
    short8 r;
    r[0] = (short)f2bf(lo.x); r[1] = (short)f2bf(lo.y);
    r[2] = (short)f2bf(lo.z); r[3] = (short)f2bf(lo.w);
    r[4] = (short)f2bf(hi.x); r[5] = (short)f2bf(hi.y);
    r[6] = (short)f2bf(hi.z); r[7] = (short)f2bf(hi.w);
    return r;
}

// ---------------------------------------------------------------------------
// One-off: Wb[o][k] = bf16(W[o][k])
// ---------------------------------------------------------------------------
__global__ __launch_bounds__(256) void k_wb(const float* __restrict__ W,
                                            unsigned short* __restrict__ Wb) {
    const int i = blockIdx.x * 256 + threadIdx.x;
    Wb[i] = f2bf(W[i]);
}

// ---------------------------------------------------------------------------
// Kernel 1: zero-LDS bf16 MFMA GEMM + FUSED bucket histogram.
// GEMM part identical to round-10 (verified absmax 1.0). Blocks 0..NB-1
// additionally histogram their COO chunk after the C-store (independent
// work, disjoint pipes: GEMM = VMEM/MFMA, hist = LDS atomics).
// ---------------------------------------------------------------------------
__global__ __launch_bounds__(256) void k_project(const float* __restrict__ X,
                                                 const unsigned short* __restrict__ Wb,
                                                 unsigned short* __restrict__ Xpb,
                                                 const int* __restrict__ v_idx,
                                                 const int* __restrict__ e_idx,
                                                 int* __restrict__ mat) {
    __shared__ int h[NBINS];   // 9.4 KB; used only by blocks < NB
    const int tid  = threadIdx.x;
    const int lane = tid & 63;
    const int wv   = tid >> 6;
    const int l15  = lane & 15;
    const int l4   = lane >> 4;
    const int rbase = blockIdx.x * 128 + wv * 32;

    const bool doHist = (blockIdx.x < NB);
    if (doHist) {
        for (int i = tid; i < NBINS; i += 256) h[i] = 0;
    }

    const int r0 = min(rbase + l15,      NV - 1);
    const int r1 = min(rbase + 16 + l15, NV - 1);
    const float* xp0 = X + (size_t)r0 * KIN + l4 * 8;
    const float* xp1 = X + (size_t)r1 * KIN + l4 * 8;
    const unsigned short* wp = Wb + (size_t)l15 * KIN + l4 * 8;

    f32x4 acc[2][4];
#pragma unroll
    for (int t = 0; t < 2; ++t)
#pragma unroll
        for (int g = 0; g < 4; ++g)
            acc[t][g] = (f32x4){0.f, 0.f, 0.f, 0.f};

#pragma unroll
    for (int s = 0; s < 8; ++s) {
        const int k0 = s * 32;
        const float4 a0lo = *(const float4*)(xp0 + k0);
        const float4 a0hi = *(const float4*)(xp0 + k0 + 4);
        const float4 a1lo = *(const float4*)(xp1 + k0);
        const float4 a1hi = *(const float4*)(xp1 + k0 + 4);
        short8 b[4];
#pragma unroll
        for (int g = 0; g < 4; ++g)
            b[g] = *(const short8*)(wp + (size_t)g * 16 * KIN + k0);
        const short8 a0 = pack8(a0lo, a0hi);
        const short8 a1 = pack8(a1lo, a1hi);
#pragma unroll
        for (int g = 0; g < 4; ++g) {
            acc[0][g] = __builtin_amdgcn_mfma_f32_16x16x32_bf16(a0, b[g], acc[0][g], 0, 0, 0);
            acc[1][g] = __builtin_amdgcn_mfma_f32_16x16x32_bf16(a1, b[g], acc[1][g], 0, 0, 0);
        }
    }

#pragma unroll
    for (int t = 0; t < 2; ++t)
#pragma unroll
        for (int i = 0; i < 4; ++i) {
            const int r = rbase + t * 16 + l4 * 4 + i;
            if (r < NV) {
#pragma unroll
                for (int g = 0; g < 4; ++g)
                    Xpb[(size_t)r * KOUT + g * 16 + l15] = f2bf(acc[t][g][i]);
            }
        }

    if (doHist) {
        __syncthreads();   // h[] zeroing done (block-uniform branch)
        const int base = blockIdx.x * CHUNK;
        for (int i = tid; i < CHUNK; i += 256) {
            atomicAdd(&h[e_idx[base + i] >> 6], 1);
            atomicAdd(&h[NBE + (v_idx[base + i] >> 6)], 1);
        }
        __syncthreads();
        for (int j = tid; j < NBINS; j += 256) mat[j * NB + blockIdx.x] = h[j];
    }
}

// ---------------------------------------------------------------------------
// 3-kernel exclusive scan of mat[LSCAN]
// ---------------------------------------------------------------------------
__global__ __launch_bounds__(1024) void k_scan1(int* __restrict__ mat,
                                                int* __restrict__ bsum) {
    __shared__ int buf[1024];
    const int tid = threadIdx.x;
    const int i = blockIdx.x * 1024 + tid;
    const int v = (i < LSCAN) ? mat[i] : 0;
    buf[tid] = v;
    __syncthreads();
    for (int d = 1; d < 1024; d <<= 1) {
        int t = (tid >= d) ? buf[tid - d] : 0;
        __syncthreads();
        buf[tid] += t;
        __syncthreads();
    }
    if (i < LSCAN) mat[i] = buf[tid] - v;
    if (tid == 1023) bsum[blockIdx.x] = buf[1023];
}

__global__ __launch_bounds__(1024) void k_scan2(int* __restrict__ bsum) {
    __shared__ int buf[1024];
    const int tid = threadIdx.x;
    const int v = (tid < NBLK_SCAN) ? bsum[tid] : 0;
    buf[tid] = v;
    __syncthreads();
    for (int d = 1; d < 1024; d <<= 1) {
        int t = (tid >= d) ? buf[tid - d] : 0;
        __syncthreads();
        buf[tid] += t;
        __syncthreads();
    }
    if (tid < NBLK_SCAN) bsum[tid] = buf[tid] - v;
}

__global__ __launch_bounds__(1024) void k_scan3(int* __restrict__ mat,
                                                const int* __restrict__ bsum) {
    const int i = blockIdx.x * 1024 + threadIdx.x;
    if (i < LSCAN) mat[i] += bsum[blockIdx.x];
}

// ---------------------------------------------------------------------------
// Fused partition (1024 thr): ONE pass writes BOTH bucket-ordered arrays.
//   partE[p] = v | ((e&63)<<17)      partV[p] = e | ((v&63)<<17)
// ---------------------------------------------------------------------------
__global__ __launch_bounds__(1024) void k_partition2(const int* __restrict__ v_idx,
                                                     const int* __restrict__ e_idx,
                                                     const int* __restrict__ mat,
                                                     unsigned* __restrict__ partE,
                                                     unsigned* __restrict__ partV) {
    __shared__ int curE[NBE];
    __shared__ int curV[NBV];
    const int b = blockIdx.x, tid = threadIdx.x;
    for (int j = tid; j < NBE; j += 1024) curE[j] = mat[j * NB + b];
    for (int j = tid; j < NBV; j += 1024) curV[j] = mat[(NBE + j) * NB + b] - NNZ;
    __syncthreads();
    const int base = b * CHUNK;
    for (int i = tid; i < CHUNK; i += 1024) {
        const int v = v_idx[base + i];
        const int e = e_idx[base + i];
        const int pE = atomicAdd(&curE[e >> 6], 1);
        partE[pE] = (unsigned)v | ((unsigned)(e & 63) << 17);
        const int pV = atomicAdd(&curV[v >> 6], 1);
        partV[pV] = (unsigned)e | ((unsigned)(v & 63) << 17);
    }
}

// ---------------------------------------------------------------------------
// Fused sort+gather, edge side: one block per 64-edge bucket.
// LDS counting sort, then EIGHTH-wave gather: lane -> 8 channels (uint4),
// 8 lanes/row, 8 entries per load round. bf16 row writes.
// ---------------------------------------------------------------------------
__global__ __launch_bounds__(1024) void k_sortgatherE(const unsigned* __restrict__ part,
                                                      const int* __restrict__ mat,
                                                      const unsigned short* __restrict__ Xpb,
                                                      const float* __restrict__ degE,
                                                      const float* __restrict__ Wdiag,
                                                      unsigned short* __restrict__ Xeb) {
    __shared__ unsigned sbuf[ECAP_E];       // 24 KB
    __shared__ int hist[64], cur[64], pfx[65];
    const int b = blockIdx.x, tid = threadIdx.x;
    const int base = mat[b * NB];
    const int end  = (b == NBE - 1) ? NNZ : mat[(b + 1) * NB];
    const int nb = end - base;

    if (tid < 64) hist[tid] = 0;
    __syncthreads();
    for (int i = tid; i < nb; i += 1024)
        atomicAdd(&hist[(part[base + i] >> 17) & 63], 1);
    __syncthreads();
    if (tid == 0) {
        int s = 0;
        for (int k = 0; k < 64; ++k) { pfx[k] = s; cur[k] = s; s += hist[k]; }
        pfx[64] = s;
    }
    __syncthreads();
    for (int i = tid; i < nb; i += 1024) {
        const unsigned u = part[base + i];
        const int p = atomicAdd(&cur[(u >> 17) & 63], 1);
        sbuf[p] = u & 0x1FFFFu;
    }
    __syncthreads();

    const int wv = tid >> 6, lane = tid & 63;
    const int q = lane >> 3, sl = lane & 7;          // 8 entries x 8 ch-groups
#pragma unroll
    for (int j = 0; j < 4; ++j) {
        const int le = wv * 4 + j;
        const int e_id = (b << 6) + le;
        const int s0 = pfx[le];
        const int n  = pfx[le + 1] - s0;
        float a0 = 0.f, a1 = 0.f, a2 = 0.f, a3 = 0.f,
              a4 = 0.f, a5 = 0.f, a6 = 0.f, a7 = 0.f;
        const int nf = n >> 3;
        int t = 0;
        for (; t + 4 <= nf; t += 4) {
            int idx[4]; uint4 u4[4];
#pragma unroll
            for (int z = 0; z < 4; ++z) idx[z] = (int)sbuf[s0 + 8 * (t + z) + q];
#pragma unroll
            for (int z = 0; z < 4; ++z)
                u4[z] = *(const uint4*)&Xpb[(size_t)idx[z] * KOUT + 8 * sl];
#pragma unroll
            for (int z = 0; z < 4; ++z) {
                a0 += bf2f_lo(u4[z].x); a1 += bf2f_hi(u4[z].x);
                a2 += bf2f_lo(u4[z].y); a3 += bf2f_hi(u4[z].y);
                a4 += bf2f_lo(u4[z].z); a5 += bf2f_hi(u4[z].z);
                a6 += bf2f_lo(u4[z].w); a7 += bf2f_hi(u4[z].w);
            }
        }
        for (; t < nf; ++t) {
            const int idx = (int)sbuf[s0 + 8 * t + q];
            const uint4 u = *(const uint4*)&Xpb[(size_t)idx * KOUT + 8 * sl];
            a0 += bf2f_lo(u.x); a1 += bf2f_hi(u.x);
            a2 += bf2f_lo(u.y); a3 += bf2f_hi(u.y);
            a4 += bf2f_lo(u.z); a5 += bf2f_hi(u.z);
            a6 += bf2f_lo(u.w); a7 += bf2f_hi(u.w);
        }
        if (n & 7) {
            const int src = nf * 8 + q;
            if (src < n) {
                const int idx = (int)sbuf[s0 + src];
                const uint4 u = *(const uint4*)&Xpb[(size_t)idx * KOUT + 8 * sl];
                a0 += bf2f_lo(u.x); a1 += bf2f_hi(u.x);
                a2 += bf2f_lo(u.y); a3 += bf2f_hi(u.y);
                a4 += bf2f_lo(u.z); a5 += bf2f_hi(u.z);
                a6 += bf2f_lo(u.w); a7 += bf2f_hi(u.w);
            }
        }
#pragma unroll
        for (int d = 8; d < 64; d <<= 1) {
            a0 += __shfl_xor(a0, d, 64); a1 += __shfl_xor(a1, d, 64);
            a2 += __shfl_xor(a2, d, 64); a3 += __shfl_xor(a3, d, 64);
            a4 += __shfl_xor(a4, d, 64); a5 += __shfl_xor(a5, d, 64);
            a6 += __shfl_xor(a6, d, 64); a7 += __shfl_xor(a7, d, 64);
        }
        if (q == 0 && e_id < NE) {
            const float s = degE[e_id] * Wdiag[e_id];
            uint4 pk;
            pk.x = (unsigned)f2bf(a0 * s) | ((unsigned)f2bf(a1 * s) << 16);
            pk.y = (unsigned)f2bf(a2 * s) | ((unsigned)f2bf(a3 * s) << 16);
            pk.z = (unsigned)f2bf(a4 * s) | ((unsigned)f2bf(a5 * s) << 16);
            pk.w = (unsigned)f2bf(a6 * s) | ((unsigned)f2bf(a7 * s) << 16);
            *(uint4*)&Xeb[(size_t)e_id * KOUT + 8 * sl] = pk;
        }
    }
}

// ---------------------------------------------------------------------------
// Fused sort+gather, vertex side: one block per 64-vertex bucket; f32 out.
// ---------------------------------------------------------------------------
__global__ __launch_bounds__(1024) void k_sortgatherV(const unsigned* __restrict__ part,
                                                      const int* __restrict__ mat,
                                                      const unsigned short* __restrict__ Xeb,
                                                      const float* __restrict__ degV,
                                                      float* __restrict__ out) {
    __shared__ unsigned sbuf[ECAP_V];       // 16 KB
    __shared__ int hist[64], cur[64], pfx[65];
    const int b = blockIdx.x, tid = threadIdx.x;
    const int base = mat[NBE * NB + b * NB] - NNZ;
    const int end  = (b == NBV - 1) ? NNZ : (mat[NBE * NB + (b + 1) * NB] - NNZ);
    const int nb = end - base;

    if (tid < 64) hist[tid] = 0;
    __syncthreads();
    for (int i = tid; i < nb; i += 1024)
        atomicAdd(&hist[(part[base + i] >> 17) & 63], 1);
    __syncthreads();
    if (tid == 0) {
        int s = 0;
        for (int k = 0; k < 64; ++k) { pfx[k] = s; cur[k] = s; s += hist[k]; }
        pfx[64] = s;
    }
    __syncthreads();
    for (int i = tid; i < nb; i += 1024) {
        const unsigned u = part[base + i];
        const int p = atomicAdd(&cur[(u >> 17) & 63], 1);
        sbuf[p] = u & 0x1FFFFu;
    }
    __syncthreads();

    const int wv = tid >> 6, lane = tid & 63;
    const int q = lane >> 3, sl = lane & 7;
#pragma unroll
    for (int j = 0; j < 4; ++j) {
        const int lv = wv * 4 + j;
        const int v_id = (b << 6) + lv;
        const int s0 = pfx[lv];
        const int n  = pfx[lv + 1] - s0;
        float a0 = 0.f, a1 = 0.f, a2 = 0.f, a3 = 0.f,
              a4 = 0.f, a5 = 0.f, a6 = 0.f, a7 = 0.f;
        const int nf = n >> 3;
        int t = 0;
        for (; t + 4 <= nf; t += 4) {
            int idx[4]; uint4 u4[4];
#pragma unroll
            for (int z = 0; z < 4; ++z) idx[z] = (int)sbuf[s0 + 8 * (t + z) + q];
#pragma unroll
            for (int z = 0; z < 4; ++z)
                u4[z] = *(const uint4*)&Xeb[(size_t)idx[z] * KOUT + 8 * sl];
#pragma unroll
            for (int z = 0; z < 4; ++z) {
                a0 += bf2f_lo(u4[z].x); a1 += bf2f_hi(u4[z].x);
                a2 += bf2f_lo(u4[z].y); a3 += bf2f_hi(u4[z].y);
                a4 += bf2f_lo(u4[z].z); a5 += bf2f_hi(u4[z].z);
                a6 += bf2f_lo(u4[z].w); a7 += bf2f_hi(u4[z].w);
            }
        }
        for (; t < nf; ++t) {
            const int idx = (int)sbuf[s0 + 8 * t + q];
            const uint4 u = *(const uint4*)&Xeb[(size_t)idx * KOUT + 8 * sl];
            a0 += bf2f_lo(u.x); a1 += bf2f_hi(u.x);
            a2 += bf2f_lo(u.y); a3 += bf2f_hi(u.y);
            a4 += bf2f_lo(u.z); a5 += bf2f_hi(u.z);
            a6 += bf2f_lo(u.w); a7 += bf2f_hi(u.w);
        }
        if (n & 7) {
            const int src = nf * 8 + q;
            if (src < n) {
                const int idx = (int)sbuf[s0 + src];
                const uint4 u = *(const uint4*)&Xeb[(size_t)idx * KOUT + 8 * sl];
                a0 += bf2f_lo(u.x); a1 += bf2f_hi(u.x);
                a2 += bf2f_lo(u.y); a3 += bf2f_hi(u.y);
                a4 += bf2f_lo(u.z); a5 += bf2f_hi(u.z);
                a6 += bf2f_lo(u.w); a7 += bf2f_hi(u.w);
            }
        }
#pragma unroll
        for (int d = 8; d < 64; d <<= 1) {
            a0 += __shfl_xor(a0, d, 64); a1 += __shfl_xor(a1, d, 64);
            a2 += __shfl_xor(a2, d, 64); a3 += __shfl_xor(a3, d, 64);
            a4 += __shfl_xor(a4, d, 64); a5 += __shfl_xor(a5, d, 64);
            a6 += __shfl_xor(a6, d, 64); a7 += __shfl_xor(a7, d, 64);
        }
        if (q == 0 && v_id < NV) {
            const float s = degV[v_id];
            *(float4*)&out[(size_t)v_id * KOUT + 8 * sl] =
                make_float4(a0 * s, a1 * s, a2 * s, a3 * s);
            *(float4*)&out[(size_t)v_id * KOUT + 8 * sl + 4] =
                make_float4(a4 * s, a5 * s, a6 * s, a7 * s);
        }
    }
}

extern "C" void kernel_launch(void* const* d_in, const int* in_sizes, int n_in,
                              void* d_out, int out_size, void* d_ws, size_t ws_size,
                              hipStream_t stream) {
    const float* X     = (const float*)d_in[0];
    const float* W     = (const float*)d_in[1];
    const float* degE  = (const float*)d_in[2];
    const float* degV  = (const float*)d_in[3];
    const float* Wdiag = (const float*)d_in[4];
    const int*   v_idx = (const int*)d_in[5];
    const int*   e_idx = (const int*)d_in[6];
    float* out = (float*)d_out;

    // Workspace (~46 MB)
    unsigned short* Xpb  = (unsigned short*)d_ws;             // NV*KOUT bf16
    unsigned short* Xeb  = Xpb + (size_t)NV * KOUT;           // NE*KOUT bf16
    unsigned*       partE = (unsigned*)(Xeb + (size_t)NE * KOUT); // NNZ u32
    unsigned*       partV = partE + NNZ;                      // NNZ u32
    int*            mat   = (int*)(partV + NNZ);              // LSCAN
    int*            bsum  = mat + LSCAN;                      // NBLK_SCAN
    unsigned short* Wb    = (unsigned short*)(bsum + ((NBLK_SCAN + 3) & ~3)); // 32 KB

    k_wb<<<(KIN * KOUT) / 256, 256, 0, stream>>>(W, Wb);
    // GEMM + fused histogram (blocks 0..NB-1 also hist their COO chunk)
    k_project<<<(NV + 127) / 128, 256, 0, stream>>>(X, Wb, Xpb, v_idx, e_idx, mat);

    k_scan1<<<NBLK_SCAN, 1024, 0, stream>>>(mat, bsum);
    k_scan2<<<1, 1024, 0, stream>>>(bsum);
    k_scan3<<<NBLK_SCAN, 1024, 0, stream>>>(mat, bsum);

    // One fused pass writes both bucket-ordered arrays
    k_partition2<<<NB, 1024, 0, stream>>>(v_idx, e_idx, mat, partE, partV);

    // Fused per-bucket sort + gather
    k_sortgatherE<<<NBE, 1024, 0, stream>>>(partE, mat, Xpb, degE, Wdiag, Xeb);
    k_sortgatherV<<<NBV, 1024, 0, stream>>>(partV, mat, Xeb, degV, out);
}

// Round 17
// 238.736 us; speedup vs baseline: 1.2767x; 1.1175x over previous
//
#include <hip/hip_runtime.h>

#define NV   100000
#define NE   50000
#define NNZ  3200000
#define KIN  256
#define KOUT 64

#define NB    128                  // hist/partition chunks (NNZ = 128*25000 exactly)
#define CHUNK (NNZ / NB)           // 25000
#define NBE   782                  // ceil(NE/64) edge buckets
#define NBV   1563                 // ceil(NV/64) vertex buckets
#define NBINS (NBE + NBV)          // 2345
#define LSCAN (NBINS * NB)         // 300160
#define NBLK_SCAN ((LSCAN + 1023) / 1024)   // 294 (<= 1024 for k_scan2)

#define ECAP_E 6144                // E-bucket LDS capacity (mean 4096)
#define ECAP_V 4096                // V-bucket LDS capacity (mean 2048)

typedef short short8 __attribute__((ext_vector_type(8)));
typedef float f32x4  __attribute__((ext_vector_type(4)));

__device__ __forceinline__ unsigned short f2bf(float f) {
    union { float f; unsigned u; } c{f};
    const unsigned lsb = (c.u >> 16) & 1u;
    return (unsigned short)((c.u + 0x7FFFu + lsb) >> 16);
}
__device__ __forceinline__ float bf2f_lo(unsigned u) {
    union { unsigned u; float f; } c{u << 16};
    return c.f;
}
__device__ __forceinline__ float bf2f_hi(unsigned u) {
    union { unsigned u; float f; } c{u & 0xFFFF0000u};
    return c.f;
}
__device__ __forceinline__ short8 pack8(const float4 lo, const float4 hi) {
    short8 r;
    r[0] = (short)f2bf(lo.x); r[1] = (short)f2bf(lo.y);
    r[2] = (short)f2bf(lo.z); r[3] = (short)f2bf(lo.w);
    r[4] = (short)f2bf(hi.x); r[5] = (short)f2bf(hi.y);
    r[6] = (short)f2bf(hi.z); r[7] = (short)f2bf(hi.w);
    return r;
}

// ---------------------------------------------------------------------------
// One-off: Wb[o][k] = bf16(W[o][k])
// ---------------------------------------------------------------------------
__global__ __launch_bounds__(256) void k_wb(const float* __restrict__ W,
                                            unsigned short* __restrict__ Wb) {
    const int i = blockIdx.x * 256 + threadIdx.x;
    Wb[i] = f2bf(W[i]);
}

// ---------------------------------------------------------------------------
// Kernel 1: zero-LDS bf16 MFMA GEMM (round-10 form, verified absmax 1.0)
// ---------------------------------------------------------------------------
__global__ __launch_bounds__(256) void k_project(const float* __restrict__ X,
                                                 const unsigned short* __restrict__ Wb,
                                                 unsigned short* __restrict__ Xpb) {
    const int tid  = threadIdx.x;
    const int lane = tid & 63;
    const int wv   = tid >> 6;
    const int l15  = lane & 15;
    const int l4   = lane >> 4;
    const int rbase = blockIdx.x * 128 + wv * 32;

    const int r0 = min(rbase + l15,      NV - 1);
    const int r1 = min(rbase + 16 + l15, NV - 1);
    const float* xp0 = X + (size_t)r0 * KIN + l4 * 8;
    const float* xp1 = X + (size_t)r1 * KIN + l4 * 8;
    const unsigned short* wp = Wb + (size_t)l15 * KIN + l4 * 8;

    f32x4 acc[2][4];
#pragma unroll
    for (int t = 0; t < 2; ++t)
#pragma unroll
        for (int g = 0; g < 4; ++g)
            acc[t][g] = (f32x4){0.f, 0.f, 0.f, 0.f};

#pragma unroll
    for (int s = 0; s < 8; ++s) {
        const int k0 = s * 32;
        const float4 a0lo = *(const float4*)(xp0 + k0);
        const float4 a0hi = *(const float4*)(xp0 + k0 + 4);
        const float4 a1lo = *(const float4*)(xp1 + k0);
        const float4 a1hi = *(const float4*)(xp1 + k0 + 4);
        short8 b[4];
#pragma unroll
        for (int g = 0; g < 4; ++g)
            b[g] = *(const short8*)(wp + (size_t)g * 16 * KIN + k0);
        const short8 a0 = pack8(a0lo, a0hi);
        const short8 a1 = pack8(a1lo, a1hi);
#pragma unroll
        for (int g = 0; g < 4; ++g) {
            acc[0][g] = __builtin_amdgcn_mfma_f32_16x16x32_bf16(a0, b[g], acc[0][g], 0, 0, 0);
            acc[1][g] = __builtin_amdgcn_mfma_f32_16x16x32_bf16(a1, b[g], acc[1][g], 0, 0, 0);
        }
    }

#pragma unroll
    for (int t = 0; t < 2; ++t)
#pragma unroll
        for (int i = 0; i < 4; ++i) {
            const int r = rbase + t * 16 + l4 * 4 + i;
            if (r < NV) {
#pragma unroll
                for (int g = 0; g < 4; ++g)
                    Xpb[(size_t)r * KOUT + g * 16 + l15] = f2bf(acc[t][g][i]);
            }
        }
}

// ---------------------------------------------------------------------------
// Per-block LDS histogram of BOTH bucket keys -> count matrix (1024 thr)
// ---------------------------------------------------------------------------
__global__ __launch_bounds__(1024) void k_hist(const int* __restrict__ v_idx,
                                               const int* __restrict__ e_idx,
                                               int* __restrict__ mat) {
    __shared__ int h[NBINS];
    const int b = blockIdx.x, tid = threadIdx.x;
    for (int i = tid; i < NBINS; i += 1024) h[i] = 0;
    __syncthreads();
    const int base = b * CHUNK;
    for (int i = tid; i < CHUNK; i += 1024) {
        atomicAdd(&h[e_idx[base + i] >> 6], 1);
        atomicAdd(&h[NBE + (v_idx[base + i] >> 6)], 1);
    }
    __syncthreads();
    for (int j = tid; j < NBINS; j += 1024) mat[j * NB + b] = h[j];
}

// ---------------------------------------------------------------------------
// 3-kernel exclusive scan of mat[LSCAN]
// ---------------------------------------------------------------------------
__global__ __launch_bounds__(1024) void k_scan1(int* __restrict__ mat,
                                                int* __restrict__ bsum) {
    __shared__ int buf[1024];
    const int tid = threadIdx.x;
    const int i = blockIdx.x * 1024 + tid;
    const int v = (i < LSCAN) ? mat[i] : 0;
    buf[tid] = v;
    __syncthreads();
    for (int d = 1; d < 1024; d <<= 1) {
        int t = (tid >= d) ? buf[tid - d] : 0;
        __syncthreads();
        buf[tid] += t;
        __syncthreads();
    }
    if (i < LSCAN) mat[i] = buf[tid] - v;
    if (tid == 1023) bsum[blockIdx.x] = buf[1023];
}

__global__ __launch_bounds__(1024) void k_scan2(int* __restrict__ bsum) {
    __shared__ int buf[1024];
    const int tid = threadIdx.x;
    const int v = (tid < NBLK_SCAN) ? bsum[tid] : 0;
    buf[tid] = v;
    __syncthreads();
    for (int d = 1; d < 1024; d <<= 1) {
        int t = (tid >= d) ? buf[tid - d] : 0;
        __syncthreads();
        buf[tid] += t;
        __syncthreads();
    }
    if (tid < NBLK_SCAN) bsum[tid] = buf[tid] - v;
}

__global__ __launch_bounds__(1024) void k_scan3(int* __restrict__ mat,
                                                const int* __restrict__ bsum) {
    const int i = blockIdx.x * 1024 + threadIdx.x;
    if (i < LSCAN) mat[i] += bsum[blockIdx.x];
}

// ---------------------------------------------------------------------------
// Fused partition (1024 thr): ONE pass writes BOTH bucket-ordered arrays.
//   partE[p] = v | ((e&63)<<17)      partV[p] = e | ((v&63)<<17)
// ---------------------------------------------------------------------------
__global__ __launch_bounds__(1024) void k_partition2(const int* __restrict__ v_idx,
                                                     const int* __restrict__ e_idx,
                                                     const int* __restrict__ mat,
                                                     unsigned* __restrict__ partE,
                                                     unsigned* __restrict__ partV) {
    __shared__ int curE[NBE];
    __shared__ int curV[NBV];
    const int b = blockIdx.x, tid = threadIdx.x;
    for (int j = tid; j < NBE; j += 1024) curE[j] = mat[j * NB + b];
    for (int j = tid; j < NBV; j += 1024) curV[j] = mat[(NBE + j) * NB + b] - NNZ;
    __syncthreads();
    const int base = b * CHUNK;
    for (int i = tid; i < CHUNK; i += 1024) {
        const int v = v_idx[base + i];
        const int e = e_idx[base + i];
        const int pE = atomicAdd(&curE[e >> 6], 1);
        partE[pE] = (unsigned)v | ((unsigned)(e & 63) << 17);
        const int pV = atomicAdd(&curV[v >> 6], 1);
        partV[pV] = (unsigned)e | ((unsigned)(v & 63) << 17);
    }
}

// ---------------------------------------------------------------------------
// Fused sort+gather, edge side: one block per 64-edge bucket.
// LDS counting sort, then EIGHTH-wave gather: lane -> 8 channels (uint4),
// 8 lanes/row, 8 entries per load round. bf16 row writes.
// ---------------------------------------------------------------------------
__global__ __launch_bounds__(1024) void k_sortgatherE(const unsigned* __restrict__ part,
                                                      const int* __restrict__ mat,
                                                      const unsigned short* __restrict__ Xpb,
                                                      const float* __restrict__ degE,
                                                      const float* __restrict__ Wdiag,
                                                      unsigned short* __restrict__ Xeb) {
    __shared__ unsigned sbuf[ECAP_E];       // 24 KB
    __shared__ int hist[64], cur[64], pfx[65];
    const int b = blockIdx.x, tid = threadIdx.x;
    const int base = mat[b * NB];
    const int end  = (b == NBE - 1) ? NNZ : mat[(b + 1) * NB];
    const int nb = end - base;

    if (tid < 64) hist[tid] = 0;
    __syncthreads();
    for (int i = tid; i < nb; i += 1024)
        atomicAdd(&hist[(part[base + i] >> 17) & 63], 1);
    __syncthreads();
    if (tid == 0) {
        int s = 0;
        for (int k = 0; k < 64; ++k) { pfx[k] = s; cur[k] = s; s += hist[k]; }
        pfx[64] = s;
    }
    __syncthreads();
    for (int i = tid; i < nb; i += 1024) {
        const unsigned u = part[base + i];
        const int p = atomicAdd(&cur[(u >> 17) & 63], 1);
        sbuf[p] = u & 0x1FFFFu;
    }
    __syncthreads();

    const int wv = tid >> 6, lane = tid & 63;
    const int q = lane >> 3, sl = lane & 7;          // 8 entries x 8 ch-groups
#pragma unroll
    for (int j = 0; j < 4; ++j) {
        const int le = wv * 4 + j;
        const int e_id = (b << 6) + le;
        const int s0 = pfx[le];
        const int n  = pfx[le + 1] - s0;
        float a0 = 0.f, a1 = 0.f, a2 = 0.f, a3 = 0.f,
              a4 = 0.f, a5 = 0.f, a6 = 0.f, a7 = 0.f;
        const int nf = n >> 3;
        int t = 0;
        for (; t + 4 <= nf; t += 4) {
            int idx[4]; uint4 u4[4];
#pragma unroll
            for (int z = 0; z < 4; ++z) idx[z] = (int)sbuf[s0 + 8 * (t + z) + q];
#pragma unroll
            for (int z = 0; z < 4; ++z)
                u4[z] = *(const uint4*)&Xpb[(size_t)idx[z] * KOUT + 8 * sl];
#pragma unroll
            for (int z = 0; z < 4; ++z) {
                a0 += bf2f_lo(u4[z].x); a1 += bf2f_hi(u4[z].x);
                a2 += bf2f_lo(u4[z].y); a3 += bf2f_hi(u4[z].y);
                a4 += bf2f_lo(u4[z].z); a5 += bf2f_hi(u4[z].z);
                a6 += bf2f_lo(u4[z].w); a7 += bf2f_hi(u4[z].w);
            }
        }
        for (; t < nf; ++t) {
            const int idx = (int)sbuf[s0 + 8 * t + q];
            const uint4 u = *(const uint4*)&Xpb[(size_t)idx * KOUT + 8 * sl];
            a0 += bf2f_lo(u.x); a1 += bf2f_hi(u.x);
            a2 += bf2f_lo(u.y); a3 += bf2f_hi(u.y);
            a4 += bf2f_lo(u.z); a5 += bf2f_hi(u.z);
            a6 += bf2f_lo(u.w); a7 += bf2f_hi(u.w);
        }
        if (n & 7) {
            const int src = nf * 8 + q;
            if (src < n) {
                const int idx = (int)sbuf[s0 + src];
                const uint4 u = *(const uint4*)&Xpb[(size_t)idx * KOUT + 8 * sl];
                a0 += bf2f_lo(u.x); a1 += bf2f_hi(u.x);
                a2 += bf2f_lo(u.y); a3 += bf2f_hi(u.y);
                a4 += bf2f_lo(u.z); a5 += bf2f_hi(u.z);
                a6 += bf2f_lo(u.w); a7 += bf2f_hi(u.w);
            }
        }
#pragma unroll
        for (int d = 8; d < 64; d <<= 1) {
            a0 += __shfl_xor(a0, d, 64); a1 += __shfl_xor(a1, d, 64);
            a2 += __shfl_xor(a2, d, 64); a3 += __shfl_xor(a3, d, 64);
            a4 += __shfl_xor(a4, d, 64); a5 += __shfl_xor(a5, d, 64);
            a6 += __shfl_xor(a6, d, 64); a7 += __shfl_xor(a7, d, 64);
        }
        if (q == 0 && e_id < NE) {
            const float s = degE[e_id] * Wdiag[e_id];
            uint4 pk;
            pk.x = (unsigned)f2bf(a0 * s) | ((unsigned)f2bf(a1 * s) << 16);
            pk.y = (unsigned)f2bf(a2 * s) | ((unsigned)f2bf(a3 * s) << 16);
            pk.z = (unsigned)f2bf(a4 * s) | ((unsigned)f2bf(a5 * s) << 16);
            pk.w = (unsigned)f2bf(a6 * s) | ((unsigned)f2bf(a7 * s) << 16);
            *(uint4*)&Xeb[(size_t)e_id * KOUT + 8 * sl] = pk;
        }
    }
}

// ---------------------------------------------------------------------------
// Fused sort+gather, vertex side: one block per 64-vertex bucket; f32 out.
// ---------------------------------------------------------------------------
__global__ __launch_bounds__(1024) void k_sortgatherV(const unsigned* __restrict__ part,
                                                      const int* __restrict__ mat,
                                                      const unsigned short* __restrict__ Xeb,
                                                      const float* __restrict__ degV,
                                                      float* __restrict__ out) {
    __shared__ unsigned sbuf[ECAP_V];       // 16 KB
    __shared__ int hist[64], cur[64], pfx[65];
    const int b = blockIdx.x, tid = threadIdx.x;
    const int base = mat[NBE * NB + b * NB] - NNZ;
    const int end  = (b == NBV - 1) ? NNZ : (mat[NBE * NB + (b + 1) * NB] - NNZ);
    const int nb = end - base;

    if (tid < 64) hist[tid] = 0;
    __syncthreads();
    for (int i = tid; i < nb; i += 1024)
        atomicAdd(&hist[(part[base + i] >> 17) & 63], 1);
    __syncthreads();
    if (tid == 0) {
        int s = 0;
        for (int k = 0; k < 64; ++k) { pfx[k] = s; cur[k] = s; s += hist[k]; }
        pfx[64] = s;
    }
    __syncthreads();
    for (int i = tid; i < nb; i += 1024) {
        const unsigned u = part[base + i];
        const int p = atomicAdd(&cur[(u >> 17) & 63], 1);
        sbuf[p] = u & 0x1FFFFu;
    }
    __syncthreads();

    const int wv = tid >> 6, lane = tid & 63;
    const int q = lane >> 3, sl = lane & 7;
#pragma unroll
    for (int j = 0; j < 4; ++j) {
        const int lv = wv * 4 + j;
        const int v_id = (b << 6) + lv;
        const int s0 = pfx[lv];
        const int n  = pfx[lv + 1] - s0;
        float a0 = 0.f, a1 = 0.f, a2 = 0.f, a3 = 0.f,
              a4 = 0.f, a5 = 0.f, a6 = 0.f, a7 = 0.f;
        const int nf = n >> 3;
        int t = 0;
        for (; t + 4 <= nf; t += 4) {
            int idx[4]; uint4 u4[4];
#pragma unroll
            for (int z = 0; z < 4; ++z) idx[z] = (int)sbuf[s0 + 8 * (t + z) + q];
#pragma unroll
            for (int z = 0; z < 4; ++z)
                u4[z] = *(const uint4*)&Xeb[(size_t)idx[z] * KOUT + 8 * sl];
#pragma unroll
            for (int z = 0; z < 4; ++z) {
                a0 += bf2f_lo(u4[z].x); a1 += bf2f_hi(u4[z].x);
                a2 += bf2f_lo(u4[z].y); a3 += bf2f_hi(u4[z].y);
                a4 += bf2f_lo(u4[z].z); a5 += bf2f_hi(u4[z].z);
                a6 += bf2f_lo(u4[z].w); a7 += bf2f_hi(u4[z].w);
            }
        }
        for (; t < nf; ++t) {
            const int idx = (int)sbuf[s0 + 8 * t + q];
            const uint4 u = *(const uint4*)&Xeb[(size_t)idx * KOUT + 8 * sl];
            a0 += bf2f_lo(u.x); a1 += bf2f_hi(u.x);
            a2 += bf2f_lo(u.y); a3 += bf2f_hi(u.y);
            a4 += bf2f_lo(u.z); a5 += bf2f_hi(u.z);
            a6 += bf2f_lo(u.w); a7 += bf2f_hi(u.w);
        }
        if (n & 7) {
            const int src = nf * 8 + q;
            if (src < n) {
                const int idx = (int)sbuf[s0 + src];
                const uint4 u = *(const uint4*)&Xeb[(size_t)idx * KOUT + 8 * sl];
                a0 += bf2f_lo(u.x); a1 += bf2f_hi(u.x);
                a2 += bf2f_lo(u.y); a3 += bf2f_hi(u.y);
                a4 += bf2f_lo(u.z); a5 += bf2f_hi(u.z);
                a6 += bf2f_lo(u.w); a7 += bf2f_hi(u.w);
            }
        }
#pragma unroll
        for (int d = 8; d < 64; d <<= 1) {
            a0 += __shfl_xor(a0, d, 64); a1 += __shfl_xor(a1, d, 64);
            a2 += __shfl_xor(a2, d, 64); a3 += __shfl_xor(a3, d, 64);
            a4 += __shfl_xor(a4, d, 64); a5 += __shfl_xor(a5, d, 64);
            a6 += __shfl_xor(a6, d, 64); a7 += __shfl_xor(a7, d, 64);
        }
        if (q == 0 && v_id < NV) {
            const float s = degV[v_id];
            *(float4*)&out[(size_t)v_id * KOUT + 8 * sl] =
                make_float4(a0 * s, a1 * s, a2 * s, a3 * s);
            *(float4*)&out[(size_t)v_id * KOUT + 8 * sl + 4] =
                make_float4(a4 * s, a5 * s, a6 * s, a7 * s);
        }
    }
}

extern "C" void kernel_launch(void* const* d_in, const int* in_sizes, int n_in,
                              void* d_out, int out_size, void* d_ws, size_t ws_size,
                              hipStream_t stream) {
    const float* X     = (const float*)d_in[0];
    const float* W     = (const float*)d_in[1];
    const float* degE  = (const float*)d_in[2];
    const float* degV  = (const float*)d_in[3];
    const float* Wdiag = (const float*)d_in[4];
    const int*   v_idx = (const int*)d_in[5];
    const int*   e_idx = (const int*)d_in[6];
    float* out = (float*)d_out;

    // Workspace (~46 MB)
    unsigned short* Xpb  = (unsigned short*)d_ws;             // NV*KOUT bf16
    unsigned short* Xeb  = Xpb + (size_t)NV * KOUT;           // NE*KOUT bf16
    unsigned*       partE = (unsigned*)(Xeb + (size_t)NE * KOUT); // NNZ u32
    unsigned*       partV = partE + NNZ;                      // NNZ u32
    int*            mat   = (int*)(partV + NNZ);              // LSCAN
    int*            bsum  = mat + LSCAN;                      // NBLK_SCAN
    unsigned short* Wb    = (unsigned short*)(bsum + ((NBLK_SCAN + 3) & ~3)); // 32 KB

    k_wb<<<(KIN * KOUT) / 256, 256, 0, stream>>>(W, Wb);
    k_project<<<(NV + 127) / 128, 256, 0, stream>>>(X, Wb, Xpb);

    k_hist<<<NB, 1024, 0, stream>>>(v_idx, e_idx, mat);
    k_scan1<<<NBLK_SCAN, 1024, 0, stream>>>(mat, bsum);
    k_scan2<<<1, 1024, 0, stream>>>(bsum);
    k_scan3<<<NBLK_SCAN, 1024, 0, stream>>>(mat, bsum);

    // One fused pass writes both bucket-ordered arrays
    k_partition2<<<NB, 1024, 0, stream>>>(v_idx, e_idx, mat, partE, partV);

    // Fused per-bucket sort + gather (eighth-wave: 8 entries/load round)
    k_sortgatherE<<<NBE, 1024, 0, stream>>>(partE, mat, Xpb, degE, Wdiag, Xeb);
    k_sortgatherV<<<NBV, 1024, 0, stream>>>(partV, mat, Xeb, degV, out);
}

// Round 18
// 224.473 us; speedup vs baseline: 1.3579x; 1.0635x over previous
//
#include <hip/hip_runtime.h>

#define NV   100000
#define NE   50000
#define NNZ  3200000
#define KIN  256
#define KOUT 64

#define NB    256                  // hist/partition chunks (NNZ = 256*12500 exactly)
#define CHUNK (NNZ / NB)           // 12500
#define TS    6250                 // partsort tile size (CHUNK = 2*TS)
#define NBE   782                  // ceil(NE/64) edge buckets
#define NBV   1563                 // ceil(NV/64) vertex buckets
#define NBINS (NBE + NBV)          // 2345
#define LSCAN (NBINS * NB)         // 600320
#define NBLK_SCAN ((LSCAN + 1023) / 1024)   // 587 (<= 1024 for k_scan2)

#define ECAP_E 6144                // E-bucket LDS capacity (mean 4096)
#define ECAP_V 4096                // V-bucket LDS capacity (mean 2048)

typedef short short8 __attribute__((ext_vector_type(8)));
typedef float f32x4  __attribute__((ext_vector_type(4)));

__device__ __forceinline__ unsigned short f2bf(float f) {
    union { float f; unsigned u; } c{f};
    const unsigned lsb = (c.u >> 16) & 1u;
    return (unsigned short)((c.u + 0x7FFFu + lsb) >> 16);
}
__device__ __forceinline__ float bf2f_lo(unsigned u) {
    union { unsigned u; float f; } c{u << 16};
    return c.f;
}
__device__ __forceinline__ float bf2f_hi(unsigned u) {
    union { unsigned u; float f; } c{u & 0xFFFF0000u};
    return c.f;
}
__device__ __forceinline__ short8 pack8(const float4 lo, const float4 hi) {
    short8 r;
    r[0] = (short)f2bf(lo.x); r[1] = (short)f2bf(lo.y);
    r[2] = (short)f2bf(lo.z); r[3] = (short)f2bf(lo.w);
    r[4] = (short)f2bf(hi.x); r[5] = (short)f2bf(hi.y);
    r[6] = (short)f2bf(hi.z); r[7] = (short)f2bf(hi.w);
    return r;
}

// ---------------------------------------------------------------------------
// One-off: Wb[o][k] = bf16(W[o][k])
// ---------------------------------------------------------------------------
__global__ __launch_bounds__(256) void k_wb(const float* __restrict__ W,
                                            unsigned short* __restrict__ Wb) {
    const int i = blockIdx.x * 256 + threadIdx.x;
    Wb[i] = f2bf(W[i]);
}

// ---------------------------------------------------------------------------
// Kernel 1: zero-LDS bf16 MFMA GEMM (round-10 form, verified absmax 1.0)
// ---------------------------------------------------------------------------
__global__ __launch_bounds__(256) void k_project(const float* __restrict__ X,
                                                 const unsigned short* __restrict__ Wb,
                                                 unsigned short* __restrict__ Xpb) {
    const int tid  = threadIdx.x;
    const int lane = tid & 63;
    const int wv   = tid >> 6;
    const int l15  = lane & 15;
    const int l4   = lane >> 4;
    const int rbase = blockIdx.x * 128 + wv * 32;

    const int r0 = min(rbase + l15,      NV - 1);
    const int r1 = min(rbase + 16 + l15, NV - 1);
    const float* xp0 = X + (size_t)r0 * KIN + l4 * 8;
    const float* xp1 = X + (size_t)r1 * KIN + l4 * 8;
    const unsigned short* wp = Wb + (size_t)l15 * KIN + l4 * 8;

    f32x4 acc[2][4];
#pragma unroll
    for (int t = 0; t < 2; ++t)
#pragma unroll
        for (int g = 0; g < 4; ++g)
            acc[t][g] = (f32x4){0.f, 0.f, 0.f, 0.f};

#pragma unroll
    for (int s = 0; s < 8; ++s) {
        const int k0 = s * 32;
        const float4 a0lo = *(const float4*)(xp0 + k0);
        const float4 a0hi = *(const float4*)(xp0 + k0 + 4);
        const float4 a1lo = *(const float4*)(xp1 + k0);
        const float4 a1hi = *(const float4*)(xp1 + k0 + 4);
        short8 b[4];
#pragma unroll
        for (int g = 0; g < 4; ++g)
            b[g] = *(const short8*)(wp + (size_t)g * 16 * KIN + k0);
        const short8 a0 = pack8(a0lo, a0hi);
        const short8 a1 = pack8(a1lo, a1hi);
#pragma unroll
        for (int g = 0; g < 4; ++g) {
            acc[0][g] = __builtin_amdgcn_mfma_f32_16x16x32_bf16(a0, b[g], acc[0][g], 0, 0, 0);
            acc[1][g] = __builtin_amdgcn_mfma_f32_16x16x32_bf16(a1, b[g], acc[1][g], 0, 0, 0);
        }
    }

#pragma unroll
    for (int t = 0; t < 2; ++t)
#pragma unroll
        for (int i = 0; i < 4; ++i) {
            const int r = rbase + t * 16 + l4 * 4 + i;
            if (r < NV) {
#pragma unroll
                for (int g = 0; g < 4; ++g)
                    Xpb[(size_t)r * KOUT + g * 16 + l15] = f2bf(acc[t][g][i]);
            }
        }
}

// ---------------------------------------------------------------------------
// Per-block LDS histogram of BOTH bucket keys -> count matrix (1024 thr)
// ---------------------------------------------------------------------------
__global__ __launch_bounds__(1024) void k_hist(const int* __restrict__ v_idx,
                                               const int* __restrict__ e_idx,
                                               int* __restrict__ mat) {
    __shared__ int h[NBINS];
    const int b = blockIdx.x, tid = threadIdx.x;
    for (int i = tid; i < NBINS; i += 1024) h[i] = 0;
    __syncthreads();
    const int base = b * CHUNK;
    for (int i = tid; i < CHUNK; i += 1024) {
        atomicAdd(&h[e_idx[base + i] >> 6], 1);
        atomicAdd(&h[NBE + (v_idx[base + i] >> 6)], 1);
    }
    __syncthreads();
    for (int j = tid; j < NBINS; j += 1024) mat[j * NB + b] = h[j];
}

// ---------------------------------------------------------------------------
// 3-kernel exclusive scan of mat[LSCAN]
// ---------------------------------------------------------------------------
__global__ __launch_bounds__(1024) void k_scan1(int* __restrict__ mat,
                                                int* __restrict__ bsum) {
    __shared__ int buf[1024];
    const int tid = threadIdx.x;
    const int i = blockIdx.x * 1024 + tid;
    const int v = (i < LSCAN) ? mat[i] : 0;
    buf[tid] = v;
    __syncthreads();
    for (int d = 1; d < 1024; d <<= 1) {
        int t = (tid >= d) ? buf[tid - d] : 0;
        __syncthreads();
        buf[tid] += t;
        __syncthreads();
    }
    if (i < LSCAN) mat[i] = buf[tid] - v;
    if (tid == 1023) bsum[blockIdx.x] = buf[1023];
}

__global__ __launch_bounds__(1024) void k_scan2(int* __restrict__ bsum) {
    __shared__ int buf[1024];
    const int tid = threadIdx.x;
    const int v = (tid < NBLK_SCAN) ? bsum[tid] : 0;
    buf[tid] = v;
    __syncthreads();
    for (int d = 1; d < 1024; d <<= 1) {
        int t = (tid >= d) ? buf[tid - d] : 0;
        __syncthreads();
        buf[tid] += t;
        __syncthreads();
    }
    if (tid < NBLK_SCAN) bsum[tid] = buf[tid] - v;
}

__global__ __launch_bounds__(1024) void k_scan3(int* __restrict__ mat,
                                                const int* __restrict__ bsum) {
    const int i = blockIdx.x * 1024 + threadIdx.x;
    if (i < LSCAN) mat[i] += bsum[blockIdx.x];
}

// ---------------------------------------------------------------------------
// Coalesced partition via per-tile LDS counting sort (SIDE 0 = E, 1 = V).
// Per tile of TS entries: hist -> wave-0 shfl-scan -> LDS scatter -> ORDERED
// write-out (consecutive lanes -> consecutive global addresses, full lines).
// Replaces the scattered-u32 partition whose stores cost ~24 B each.
// ---------------------------------------------------------------------------
template <int SIDE, int NBIN>
__global__ __launch_bounds__(1024) void k_partsort(const int* __restrict__ v_idx,
                                                   const int* __restrict__ e_idx,
                                                   const int* __restrict__ mat,
                                                   unsigned* __restrict__ part) {
    __shared__ unsigned sbuf[TS];            // 25.0 KB
    __shared__ unsigned short binbuf[TS];    // 12.5 KB
    __shared__ int hist[NBIN], pfx[NBIN], cur[NBIN], gdst[NBIN];
    const int b = blockIdx.x, tid = threadIdx.x;
    const int rowOff = SIDE ? NBE : 0;
    const int sub    = SIDE ? NNZ : 0;

    for (int j = tid; j < NBIN; j += 1024)
        gdst[j] = mat[(rowOff + j) * NB + b] - sub;

    const int base = b * CHUNK;
    for (int tile = 0; tile < CHUNK / TS; ++tile) {
        __syncthreads();
        for (int j = tid; j < NBIN; j += 1024) hist[j] = 0;
        __syncthreads();

        int sb[7]; unsigned svv[7];
#pragma unroll
        for (int s = 0; s < 7; ++s) {
            const int li = s * 1024 + tid;
            sb[s] = -1;
            if (li < TS) {
                const int i = base + tile * TS + li;
                const int v = v_idx[i], e = e_idx[i];
                int bin; unsigned val;
                if (SIDE == 0) { bin = e >> 6; val = (unsigned)v | ((unsigned)(e & 63) << 17); }
                else           { bin = v >> 6; val = (unsigned)e | ((unsigned)(v & 63) << 17); }
                atomicAdd(&hist[bin], 1);
                sb[s] = bin; svv[s] = val;
            }
        }
        __syncthreads();

        // wave 0: serial 64-chunk shfl-scan over NBIN -> exclusive pfx
        if (tid < 64) {
            int carry = 0;
            for (int c = 0; c < NBIN; c += 64) {
                const int j = c + tid;
                const int h = (j < NBIN) ? hist[j] : 0;
                int x = h;
#pragma unroll
                for (int d = 1; d < 64; d <<= 1) {
                    const int y = __shfl_up(x, d, 64);
                    if (tid >= d) x += y;
                }
                if (j < NBIN) pfx[j] = carry + x - h;
                carry += __shfl(x, 63, 64);
            }
        }
        __syncthreads();
        for (int j = tid; j < NBIN; j += 1024) cur[j] = pfx[j];
        __syncthreads();

#pragma unroll
        for (int s = 0; s < 7; ++s) {
            if (sb[s] >= 0) {
                const int p = atomicAdd(&cur[sb[s]], 1);
                sbuf[p] = svv[s];
                binbuf[p] = (unsigned short)sb[s];
            }
        }
        __syncthreads();

        // ordered write-out: consecutive li -> consecutive dest within runs
        for (int li = tid; li < TS; li += 1024) {
            const int bin = binbuf[li];
            part[gdst[bin] + (li - pfx[bin])] = sbuf[li];
        }
        __syncthreads();
        for (int j = tid; j < NBIN; j += 1024) gdst[j] += cur[j] - pfx[j];
    }
}

// ---------------------------------------------------------------------------
// Fused sort+gather, edge side: one block per 64-edge bucket.
// LDS counting sort, then EIGHTH-wave gather: lane -> 8 channels (uint4).
// ---------------------------------------------------------------------------
__global__ __launch_bounds__(1024) void k_sortgatherE(const unsigned* __restrict__ part,
                                                      const int* __restrict__ mat,
                                                      const unsigned short* __restrict__ Xpb,
                                                      const float* __restrict__ degE,
                                                      const float* __restrict__ Wdiag,
                                                      unsigned short* __restrict__ Xeb) {
    __shared__ unsigned sbuf[ECAP_E];       // 24 KB
    __shared__ int hist[64], cur[64], pfx[65];
    const int b = blockIdx.x, tid = threadIdx.x;
    const int base = mat[b * NB];
    const int end  = (b == NBE - 1) ? NNZ : mat[(b + 1) * NB];
    const int nb = end - base;

    if (tid < 64) hist[tid] = 0;
    __syncthreads();
    for (int i = tid; i < nb; i += 1024)
        atomicAdd(&hist[(part[base + i] >> 17) & 63], 1);
    __syncthreads();
    if (tid == 0) {
        int s = 0;
        for (int k = 0; k < 64; ++k) { pfx[k] = s; cur[k] = s; s += hist[k]; }
        pfx[64] = s;
    }
    __syncthreads();
    for (int i = tid; i < nb; i += 1024) {
        const unsigned u = part[base + i];
        const int p = atomicAdd(&cur[(u >> 17) & 63], 1);
        sbuf[p] = u & 0x1FFFFu;
    }
    __syncthreads();

    const int wv = tid >> 6, lane = tid & 63;
    const int q = lane >> 3, sl = lane & 7;          // 8 entries x 8 ch-groups
#pragma unroll
    for (int j = 0; j < 4; ++j) {
        const int le = wv * 4 + j;
        const int e_id = (b << 6) + le;
        const int s0 = pfx[le];
        const int n  = pfx[le + 1] - s0;
        float a0 = 0.f, a1 = 0.f, a2 = 0.f, a3 = 0.f,
              a4 = 0.f, a5 = 0.f, a6 = 0.f, a7 = 0.f;
        const int nf = n >> 3;
        int t = 0;
        for (; t + 4 <= nf; t += 4) {
            int idx[4]; uint4 u4[4];
#pragma unroll
            for (int z = 0; z < 4; ++z) idx[z] = (int)sbuf[s0 + 8 * (t + z) + q];
#pragma unroll
            for (int z = 0; z < 4; ++z)
                u4[z] = *(const uint4*)&Xpb[(size_t)idx[z] * KOUT + 8 * sl];
#pragma unroll
            for (int z = 0; z < 4; ++z) {
                a0 += bf2f_lo(u4[z].x); a1 += bf2f_hi(u4[z].x);
                a2 += bf2f_lo(u4[z].y); a3 += bf2f_hi(u4[z].y);
                a4 += bf2f_lo(u4[z].z); a5 += bf2f_hi(u4[z].z);
                a6 += bf2f_lo(u4[z].w); a7 += bf2f_hi(u4[z].w);
            }
        }
        for (; t < nf; ++t) {
            const int idx = (int)sbuf[s0 + 8 * t + q];
            const uint4 u = *(const uint4*)&Xpb[(size_t)idx * KOUT + 8 * sl];
            a0 += bf2f_lo(u.x); a1 += bf2f_hi(u.x);
            a2 += bf2f_lo(u.y); a3 += bf2f_hi(u.y);
            a4 += bf2f_lo(u.z); a5 += bf2f_hi(u.z);
            a6 += bf2f_lo(u.w); a7 += bf2f_hi(u.w);
        }
        if (n & 7) {
            const int src = nf * 8 + q;
            if (src < n) {
                const int idx = (int)sbuf[s0 + src];
                const uint4 u = *(const uint4*)&Xpb[(size_t)idx * KOUT + 8 * sl];
                a0 += bf2f_lo(u.x); a1 += bf2f_hi(u.x);
                a2 += bf2f_lo(u.y); a3 += bf2f_hi(u.y);
                a4 += bf2f_lo(u.z); a5 += bf2f_hi(u.z);
                a6 += bf2f_lo(u.w); a7 += bf2f_hi(u.w);
            }
        }
#pragma unroll
        for (int d = 8; d < 64; d <<= 1) {
            a0 += __shfl_xor(a0, d, 64); a1 += __shfl_xor(a1, d, 64);
            a2 += __shfl_xor(a2, d, 64); a3 += __shfl_xor(a3, d, 64);
            a4 += __shfl_xor(a4, d, 64); a5 += __shfl_xor(a5, d, 64);
            a6 += __shfl_xor(a6, d, 64); a7 += __shfl_xor(a7, d, 64);
        }
        if (q == 0 && e_id < NE) {
            const float s = degE[e_id] * Wdiag[e_id];
            uint4 pk;
            pk.x = (unsigned)f2bf(a0 * s) | ((unsigned)f2bf(a1 * s) << 16);
            pk.y = (unsigned)f2bf(a2 * s) | ((unsigned)f2bf(a3 * s) << 16);
            pk.z = (unsigned)f2bf(a4 * s) | ((unsigned)f2bf(a5 * s) << 16);
            pk.w = (unsigned)f2bf(a6 * s) | ((unsigned)f2bf(a7 * s) << 16);
            *(uint4*)&Xeb[(size_t)e_id * KOUT + 8 * sl] = pk;
        }
    }
}

// ---------------------------------------------------------------------------
// Fused sort+gather, vertex side: one block per 64-vertex bucket; f32 out.
// ---------------------------------------------------------------------------
__global__ __launch_bounds__(1024) void k_sortgatherV(const unsigned* __restrict__ part,
                                                      const int* __restrict__ mat,
                                                      const unsigned short* __restrict__ Xeb,
                                                      const float* __restrict__ degV,
                                                      float* __restrict__ out) {
    __shared__ unsigned sbuf[ECAP_V];       // 16 KB
    __shared__ int hist[64], cur[64], pfx[65];
    const int b = blockIdx.x, tid = threadIdx.x;
    const int base = mat[NBE * NB + b * NB] - NNZ;
    const int end  = (b == NBV - 1) ? NNZ : (mat[NBE * NB + (b + 1) * NB] - NNZ);
    const int nb = end - base;

    if (tid < 64) hist[tid] = 0;
    __syncthreads();
    for (int i = tid; i < nb; i += 1024)
        atomicAdd(&hist[(part[base + i] >> 17) & 63], 1);
    __syncthreads();
    if (tid == 0) {
        int s = 0;
        for (int k = 0; k < 64; ++k) { pfx[k] = s; cur[k] = s; s += hist[k]; }
        pfx[64] = s;
    }
    __syncthreads();
    for (int i = tid; i < nb; i += 1024) {
        const unsigned u = part[base + i];
        const int p = atomicAdd(&cur[(u >> 17) & 63], 1);
        sbuf[p] = u & 0x1FFFFu;
    }
    __syncthreads();

    const int wv = tid >> 6, lane = tid & 63;
    const int q = lane >> 3, sl = lane & 7;
#pragma unroll
    for (int j = 0; j < 4; ++j) {
        const int lv = wv * 4 + j;
        const int v_id = (b << 6) + lv;
        const int s0 = pfx[lv];
        const int n  = pfx[lv + 1] - s0;
        float a0 = 0.f, a1 = 0.f, a2 = 0.f, a3 = 0.f,
              a4 = 0.f, a5 = 0.f, a6 = 0.f, a7 = 0.f;
        const int nf = n >> 3;
        int t = 0;
        for (; t + 4 <= nf; t += 4) {
            int idx[4]; uint4 u4[4];
#pragma unroll
            for (int z = 0; z < 4; ++z) idx[z] = (int)sbuf[s0 + 8 * (t + z) + q];
#pragma unroll
            for (int z = 0; z < 4; ++z)
                u4[z] = *(const uint4*)&Xeb[(size_t)idx[z] * KOUT + 8 * sl];
#pragma unroll
            for (int z = 0; z < 4; ++z) {
                a0 += bf2f_lo(u4[z].x); a1 += bf2f_hi(u4[z].x);
                a2 += bf2f_lo(u4[z].y); a3 += bf2f_hi(u4[z].y);
                a4 += bf2f_lo(u4[z].z); a5 += bf2f_hi(u4[z].z);
                a6 += bf2f_lo(u4[z].w); a7 += bf2f_hi(u4[z].w);
            }
        }
        for (; t < nf; ++t) {
            const int idx = (int)sbuf[s0 + 8 * t + q];
            const uint4 u = *(const uint4*)&Xeb[(size_t)idx * KOUT + 8 * sl];
            a0 += bf2f_lo(u.x); a1 += bf2f_hi(u.x);
            a2 += bf2f_lo(u.y); a3 += bf2f_hi(u.y);
            a4 += bf2f_lo(u.z); a5 += bf2f_hi(u.z);
            a6 += bf2f_lo(u.w); a7 += bf2f_hi(u.w);
        }
        if (n & 7) {
            const int src = nf * 8 + q;
            if (src < n) {
                const int idx = (int)sbuf[s0 + src];
                const uint4 u = *(const uint4*)&Xeb[(size_t)idx * KOUT + 8 * sl];
                a0 += bf2f_lo(u.x); a1 += bf2f_hi(u.x);
                a2 += bf2f_lo(u.y); a3 += bf2f_hi(u.y);
                a4 += bf2f_lo(u.z); a5 += bf2f_hi(u.z);
                a6 += bf2f_lo(u.w); a7 += bf2f_hi(u.w);
            }
        }
#pragma unroll
        for (int d = 8; d < 64; d <<= 1) {
            a0 += __shfl_xor(a0, d, 64); a1 += __shfl_xor(a1, d, 64);
            a2 += __shfl_xor(a2, d, 64); a3 += __shfl_xor(a3, d, 64);
            a4 += __shfl_xor(a4, d, 64); a5 += __shfl_xor(a5, d, 64);
            a6 += __shfl_xor(a6, d, 64); a7 += __shfl_xor(a7, d, 64);
        }
        if (q == 0 && v_id < NV) {
            const float s = degV[v_id];
            *(float4*)&out[(size_t)v_id * KOUT + 8 * sl] =
                make_float4(a0 * s, a1 * s, a2 * s, a3 * s);
            *(float4*)&out[(size_t)v_id * KOUT + 8 * sl + 4] =
                make_float4(a4 * s, a5 * s, a6 * s, a7 * s);
        }
    }
}

extern "C" void kernel_launch(void* const* d_in, const int* in_sizes, int n_in,
                              void* d_out, int out_size, void* d_ws, size_t ws_size,
                              hipStream_t stream) {
    const float* X     = (const float*)d_in[0];
    const float* W     = (const float*)d_in[1];
    const float* degE  = (const float*)d_in[2];
    const float* degV  = (const float*)d_in[3];
    const float* Wdiag = (const float*)d_in[4];
    const int*   v_idx = (const int*)d_in[5];
    const int*   e_idx = (const int*)d_in[6];
    float* out = (float*)d_out;

    // Workspace (~48 MB)
    unsigned short* Xpb  = (unsigned short*)d_ws;             // NV*KOUT bf16
    unsigned short* Xeb  = Xpb + (size_t)NV * KOUT;           // NE*KOUT bf16
    unsigned*       partE = (unsigned*)(Xeb + (size_t)NE * KOUT); // NNZ u32
    unsigned*       partV = partE + NNZ;                      // NNZ u32
    int*            mat   = (int*)(partV + NNZ);              // LSCAN
    int*            bsum  = mat + LSCAN;                      // NBLK_SCAN
    unsigned short* Wb    = (unsigned short*)(bsum + ((NBLK_SCAN + 3) & ~3)); // 32 KB

    k_wb<<<(KIN * KOUT) / 256, 256, 0, stream>>>(W, Wb);
    k_project<<<(NV + 127) / 128, 256, 0, stream>>>(X, Wb, Xpb);

    k_hist<<<NB, 1024, 0, stream>>>(v_idx, e_idx, mat);
    k_scan1<<<NBLK_SCAN, 1024, 0, stream>>>(mat, bsum);
    k_scan2<<<1, 1024, 0, stream>>>(bsum);
    k_scan3<<<NBLK_SCAN, 1024, 0, stream>>>(mat, bsum);

    // Coalesced (LDS-sorted) partitions — full-line part writes
    k_partsort<0, NBE><<<NB, 1024, 0, stream>>>(v_idx, e_idx, mat, partE);
    k_partsort<1, NBV><<<NB, 1024, 0, stream>>>(v_idx, e_idx, mat, partV);

    // Fused per-bucket sort + gather (eighth-wave: 8 entries/load round)
    k_sortgatherE<<<NBE, 1024, 0, stream>>>(partE, mat, Xpb, degE, Wdiag, Xeb);
    k_sortgatherV<<<NBV, 1024, 0, stream>>>(partV, mat, Xeb, degV, out);
}